// Round 17
// baseline (399.454 us; speedup 1.0000x reference)
//
#include <hip/hip_runtime.h>

#define GDIM 7
#define NN 49            // nodes per graph
#define FDIM 1024
#define HD 8
#define CD 128
#define ODIM 256
#define NC 14
#define MAXE 12          // max incoming edges: 8 spatial + 3 knn + self

typedef __attribute__((ext_vector_type(4))) float f32x4;
typedef __attribute__((ext_vector_type(8))) short s16x8;

struct us4 { unsigned short x, y, z, w; };

__device__ __forceinline__ unsigned short f2bf(float x) {
  unsigned u = __float_as_uint(x);
  return (unsigned short)((u + 0x7fffu + ((u >> 16) & 1u)) >> 16);  // RNE
}
__device__ __forceinline__ float bf2f(unsigned short h) {
  return __uint_as_float((unsigned)h << 16);
}

#define GLOAD_LDS16(g, l)                                          \
  __builtin_amdgcn_global_load_lds(                                \
      (const __attribute__((address_space(1))) void*)(g),          \
      (__attribute__((address_space(3))) void*)(l), 16, 0, 0)

// ---------------------------------------------------------------------------
// K1: pre-pass — relu+transpose (blocks 0..4095: fp32 X + bf16 hi/lo split),
//     wconvT W1 (4096..4351), wconvT W2 (4352..4415). r15-verified.
// ---------------------------------------------------------------------------
__device__ void relu_body(char* smem, int blk, const float* __restrict__ F,
                          float* __restrict__ X,
                          unsigned short* __restrict__ Xh,
                          unsigned short* __restrict__ Xl) {
  float* lds = (float*)smem;           // 64*49 floats
  const int b  = blk >> 4;
  const int f0 = (blk & 15) << 6;
  const int tid = threadIdx.x;
  const float* src = F + (size_t)b * FDIM * NN + (size_t)f0 * NN;
  for (int idx = tid; idx < 64 * NN; idx += 256) lds[idx] = src[idx];
  __syncthreads();
  for (int pass = 0; pass < 13; pass++) {
    int n = pass * 4 + (tid >> 6);
    int fi = tid & 63;
    if (n < NN) {
      float v = lds[fi * NN + n];
      v = v > 0.f ? v : 0.f;
      size_t o = ((size_t)b * NN + n) * FDIM + f0 + fi;
      X[o] = v;
      unsigned short h = f2bf(v);
      Xh[o] = h;
      Xl[o] = f2bf(v - bf2f(h));
    }
  }
}

__device__ void wconvT_body(const float* __restrict__ W, int K, int N,
                            unsigned short* __restrict__ WhT,
                            unsigned short* __restrict__ WlT, int blk,
                            float* t /* [64*65] */) {
  const int nbx = N >> 6;
  const int bx = blk % nbx, by = blk / nbx;
  const int r0 = by << 6, c0 = bx << 6;
  const int tid = threadIdx.x;
#pragma unroll
  for (int i = 0; i < 16; i++) {
    int r = i * 4 + (tid >> 6), c = tid & 63;
    t[r * 65 + c] = W[(size_t)(r0 + r) * N + c0 + c];
  }
  __syncthreads();
#pragma unroll
  for (int i = 0; i < 16; i++) {
    int n = i * 4 + (tid >> 6);
    int k = tid & 63;
    float x = t[k * 65 + n];
    unsigned short h = f2bf(x);
    size_t o = (size_t)(c0 + n) * K + r0 + k;
    WhT[o] = h;
    WlT[o] = f2bf(x - bf2f(h));
  }
}

__global__ void __launch_bounds__(256) pre_kernel(
    const float* __restrict__ F, float* __restrict__ X,
    unsigned short* __restrict__ Xh, unsigned short* __restrict__ Xl,
    const float* __restrict__ W1, unsigned short* __restrict__ W1hT,
    unsigned short* __restrict__ W1lT, const float* __restrict__ W2,
    unsigned short* __restrict__ W2hT, unsigned short* __restrict__ W2lT) {
  __shared__ __align__(16) char smem[16640];   // max(12544, 64*65*4)
  if (blockIdx.x < 4096) {
    relu_body(smem, blockIdx.x, F, X, Xh, Xl);
  } else if (blockIdx.x < 4352) {
    wconvT_body(W1, FDIM, FDIM, W1hT, W1lT, blockIdx.x - 4096, (float*)smem);
  } else {
    wconvT_body(W2, FDIM, ODIM, W2hT, W2lT, blockIdx.x - 4352, (float*)smem);
  }
}

// ---------------------------------------------------------------------------
// knn body — register-tiled fp32 Gram (reads X row-major, r15-verified),
// top-3 + edge-list emit. LDS: xs 15232B + gram 12768B = 28000B from smem.
// ---------------------------------------------------------------------------
__device__ void knn_body(char* smem, int b, const float* __restrict__ X,
                         int* __restrict__ srcs_g, int* __restrict__ cnt_g) {
  float (*xs)[68] = (float(*)[68])(smem);
  float (*gram)[57] = (float(*)[57])(smem + 15232);
  const int tid = threadIdx.x;
  const float* Xb = X + (size_t)b * NN * FDIM;

  const int tr = tid / 14, tc = tid % 14;   // active: tid < 196
  float acc[4][4];
#pragma unroll
  for (int i = 0; i < 4; i++)
#pragma unroll
    for (int j = 0; j < 4; j++) acc[i][j] = 0.f;

  for (int c0 = 0; c0 < FDIM; c0 += 64) {
    __syncthreads();
    for (int idx = tid; idx < NN * 16; idx += 256) {
      int n = idx >> 4, q = idx & 15;
      *(float4*)&xs[n][q << 2] =
          *(const float4*)&Xb[(size_t)n * FDIM + c0 + (q << 2)];
    }
    __syncthreads();
    if (tid < 196) {
#pragma unroll
      for (int k4 = 0; k4 < 64; k4 += 4) {
        float4 a[4], bb[4];
#pragma unroll
        for (int i = 0; i < 4; i++) a[i]  = *(const float4*)&xs[tr + 14 * i][k4];
#pragma unroll
        for (int j = 0; j < 4; j++) bb[j] = *(const float4*)&xs[tc + 14 * j][k4];
#pragma unroll
        for (int i = 0; i < 4; i++)
#pragma unroll
          for (int j = 0; j < 4; j++)
            acc[i][j] += a[i].x * bb[j].x + a[i].y * bb[j].y +
                         a[i].z * bb[j].z + a[i].w * bb[j].w;
      }
    }
  }
  if (tid < 196) {
#pragma unroll
    for (int i = 0; i < 4; i++)
#pragma unroll
      for (int j = 0; j < 4; j++) gram[tr + 14 * i][tc + 14 * j] = acc[i][j];
  }
  __syncthreads();
  if (tid < NN) {
    const int n = tid;
    const float sqn = gram[n][n];
    float d0 = 1e30f, d1 = 1e30f, d2 = 1e30f;
    int i0 = 0, i1 = 0, i2 = 0;
    for (int m = 0; m < NN; m++) {
      if (m == n) continue;
      float d = sqn + gram[m][m] - 2.f * gram[n][m];
      if (d < d0)      { d2=d1; i2=i1; d1=d0; i1=i0; d0=d; i0=m; }
      else if (d < d1) { d2=d1; i2=i1; d1=d;  i1=m; }
      else if (d < d2) { d2=d;  i2=m; }
    }
    int srcs[MAXE];
    int r = n / GDIM, c = n % GDIM, k = 0;
    for (int dr = -1; dr <= 1; dr++)
      for (int dc = -1; dc <= 1; dc++) {
        if (dr == 0 && dc == 0) continue;
        int rr = r + dr, cc = c + dc;
        if (rr >= 0 && rr < GDIM && cc >= 0 && cc < GDIM)
          srcs[k++] = rr * GDIM + cc;
      }
    srcs[k++] = i0; srcs[k++] = i1; srcs[k++] = i2;
    srcs[k++] = n;   // self loop
    cnt_g[(size_t)b * NN + n] = k;
    for (int j = 0; j < MAXE; j++)
      srcs_g[((size_t)b * NN + n) * MAXE + j] = srcs[j < k ? j : 0];
  }
}

// ---------------------------------------------------------------------------
// gemm body — bf16x3-split MFMA, 128x128 tile, BK=64, XCD swizzle, XOR chunk
// swizzle (r9-verified: conflicts=0). Epilogue emits es/ed partials.
// ---------------------------------------------------------------------------
__device__ void gemm_body(
    char* smem, int bid, int NWG,
    const unsigned short* __restrict__ A_h, const unsigned short* __restrict__ A_l,
    const unsigned short* __restrict__ BT_h, const unsigned short* __restrict__ BT_l,
    float* __restrict__ C, int M, int N, int K,
    const float* __restrict__ av, const float* __restrict__ dv,
    float* __restrict__ esp, float* __restrict__ edp) {
  unsigned short (*sAh)[64] = (unsigned short(*)[64])(smem);
  unsigned short (*sAl)[64] = (unsigned short(*)[64])(smem + 16384);
  unsigned short (*sBh)[64] = (unsigned short(*)[64])(smem + 32768);
  unsigned short (*sBl)[64] = (unsigned short(*)[64])(smem + 49152);
  const int tid = threadIdx.x;
  const int w = tid >> 6, lane = tid & 63;
  const int nbx = N >> 7;
  const int q = NWG >> 3, r = NWG & 7;
  const int xcd = bid & 7, loc = bid >> 3;
  const int wg = (xcd < r) ? (xcd * (q + 1) + loc)
                           : (r * (q + 1) + (xcd - r) * q + loc);
  const int bx = wg % nbx, by = wg / nbx;
  const int row0 = by << 7, col0 = bx << 7;
  const int wr = (w >> 1) << 6, wc = (w & 1) << 6;
  const int sgr = lane >> 3;
  const int schunk = lane & 7;
  const int fr = lane & 15;
  const int fq = lane >> 4;

  f32x4 acc[4][4];
#pragma unroll
  for (int m = 0; m < 4; m++)
#pragma unroll
    for (int n = 0; n < 4; n++) acc[m][n] = (f32x4){0.f, 0.f, 0.f, 0.f};

  for (int k0 = 0; k0 < K; k0 += 64) {
    __syncthreads();
#pragma unroll
    for (int i = 0; i < 4; i++) {
      const int rbase = (w << 5) + (i << 3);
      const int gr = rbase + sgr;
      const int sc = schunk ^ (gr & 7);
      const size_t ga = (size_t)(row0 + gr) * K + k0 + (sc << 3);
      GLOAD_LDS16(A_h + ga, &sAh[rbase][0]);
      GLOAD_LDS16(A_l + ga, &sAl[rbase][0]);
      const size_t gb = (size_t)(col0 + gr) * K + k0 + (sc << 3);
      GLOAD_LDS16(BT_h + gb, &sBh[rbase][0]);
      GLOAD_LDS16(BT_l + gb, &sBl[rbase][0]);
    }
    __syncthreads();
#pragma unroll
    for (int ks = 0; ks < 2; ks++) {
      const int cb = (ks << 2) + fq;
      s16x8 ah[4], al[4], bh[4], bl[4];
#pragma unroll
      for (int m = 0; m < 4; m++) {
        const int ra = wr + (m << 4) + fr;
        const int ca = (cb ^ (ra & 7)) << 3;
        ah[m] = *(const s16x8*)&sAh[ra][ca];
        al[m] = *(const s16x8*)&sAl[ra][ca];
        const int rb = wc + (m << 4) + fr;
        const int cbn = (cb ^ (rb & 7)) << 3;
        bh[m] = *(const s16x8*)&sBh[rb][cbn];
        bl[m] = *(const s16x8*)&sBl[rb][cbn];
      }
#pragma unroll
      for (int m = 0; m < 4; m++)
#pragma unroll
        for (int n = 0; n < 4; n++) {
          acc[m][n] = __builtin_amdgcn_mfma_f32_16x16x32_bf16(ah[m], bh[n], acc[m][n], 0, 0, 0);
          acc[m][n] = __builtin_amdgcn_mfma_f32_16x16x32_bf16(ah[m], bl[n], acc[m][n], 0, 0, 0);
          acc[m][n] = __builtin_amdgcn_mfma_f32_16x16x32_bf16(al[m], bh[n], acc[m][n], 0, 0, 0);
        }
    }
  }
  const int crow = fq << 2, ccol = fr;
#pragma unroll
  for (int m = 0; m < 4; m++)
#pragma unroll
    for (int n = 0; n < 4; n++)
#pragma unroll
      for (int v = 0; v < 4; v++)
        C[(size_t)(row0 + wr + (m << 4) + crow + v) * N + col0 + wc + (n << 4) + ccol] =
            acc[m][n][v];

  // fused es/ed partial dots (owner-computes, no atomics)
  const int pstride = N >> 6;
  const int part = (col0 + wc) >> 6;
  float asv[4], adv[4];
#pragma unroll
  for (int n = 0; n < 4; n++) {
    int cidx = col0 + wc + (n << 4) + fr;
    asv[n] = av[cidx];
    adv[n] = dv[cidx];
  }
#pragma unroll
  for (int m = 0; m < 4; m++)
#pragma unroll
    for (int v = 0; v < 4; v++) {
      float s = acc[m][0][v] * asv[0] + acc[m][1][v] * asv[1] +
                acc[m][2][v] * asv[2] + acc[m][3][v] * asv[3];
      float d = acc[m][0][v] * adv[0] + acc[m][1][v] * adv[1] +
                acc[m][2][v] * adv[2] + acc[m][3][v] * adv[3];
      s += __shfl_xor(s, 1); s += __shfl_xor(s, 2);
      s += __shfl_xor(s, 4); s += __shfl_xor(s, 8);
      d += __shfl_xor(d, 1); d += __shfl_xor(d, 2);
      d += __shfl_xor(d, 4); d += __shfl_xor(d, 8);
      if (fr == 0) {
        int row = row0 + wr + (m << 4) + (fq << 2) + v;
        esp[(size_t)row * pstride + part] = s;
        edp[(size_t)row * pstride + part] = d;
      }
    }
}

// ---------------------------------------------------------------------------
// K2: knn (blocks 0..B-1, FIRST so they overlap gemm from t=0) + gemm1
//     (blocks B..B+NWG-1). __launch_bounds__(256,2) caps VGPR at 128 so the
//     branchy merge cannot repeat r13's 172-VGPR occupancy collapse; both
//     bodies fit (gemm 104, knn ~70). LDS 64KB -> 2 blocks/CU either way.
// ---------------------------------------------------------------------------
__global__ void __launch_bounds__(256, 2) knn_gemm1_kernel(
    const float* __restrict__ X, int* __restrict__ srcs_g,
    int* __restrict__ cnt_g, int B,
    const unsigned short* __restrict__ A_h, const unsigned short* __restrict__ A_l,
    const unsigned short* __restrict__ BT_h, const unsigned short* __restrict__ BT_l,
    float* __restrict__ C, int M, int N, int K, int NWG,
    const float* __restrict__ av, const float* __restrict__ dv,
    float* __restrict__ esp, float* __restrict__ edp) {
  __shared__ __align__(16) char smem[65536];
  if ((int)blockIdx.x < B) {
    knn_body(smem, blockIdx.x, X, srcs_g, cnt_g);
  } else {
    gemm_body(smem, blockIdx.x - B, NWG, A_h, A_l, BT_h, BT_l, C, M, N, K,
              av, dv, esp, edp);
  }
}

// K5: gemm2 standalone (unchanged r15 allocation, VGPR 104)
__global__ void __launch_bounds__(256) gemm_kernel(
    const unsigned short* __restrict__ A_h, const unsigned short* __restrict__ A_l,
    const unsigned short* __restrict__ BT_h, const unsigned short* __restrict__ BT_l,
    float* __restrict__ C, int M, int N, int K,
    const float* __restrict__ av, const float* __restrict__ dv,
    float* __restrict__ esp, float* __restrict__ edp) {
  __shared__ __align__(16) char smem[65536];
  gemm_body(smem, blockIdx.x, gridDim.x, A_h, A_l, BT_h, BT_l, C, M, N, K,
            av, dv, esp, edp);
}

// ---------------------------------------------------------------------------
// K4: attn1 softmax+aggregate — block per (graph,node); Z1 as bf16 hi/lo
// ---------------------------------------------------------------------------
__global__ void __launch_bounds__(256) attn1_agg(
    const float* __restrict__ H, const int* __restrict__ srcs_g,
    const int* __restrict__ cnt_g, const float* __restrict__ es1p,
    const float* __restrict__ ed1p, const float* __restrict__ b1,
    unsigned short* __restrict__ Zh, unsigned short* __restrict__ Zl) {
  const int bid = blockIdx.x;          // = b*NN + i
  const int b = bid / NN;
  const int tid = threadIdx.x;
  __shared__ int ss[MAXE];
  __shared__ float se[MAXE][HD];
  __shared__ float edv[HD];
  __shared__ float al[MAXE][HD];
  const int k = cnt_g[bid];
  if (tid < MAXE) ss[tid] = srcs_g[(size_t)bid * MAXE + tid];
  __syncthreads();
  if (tid < MAXE * HD) {
    int j = tid >> 3, h = tid & 7;
    size_t base = ((size_t)b * NN + ss[j]) * 16 + h * 2;
    se[j][h] = es1p[base] + es1p[base + 1];
  }
  if (tid >= 128 && tid < 128 + HD) {
    int h = tid - 128;
    size_t base = (size_t)bid * 16 + h * 2;
    edv[h] = ed1p[base] + ed1p[base + 1];
  }
  __syncthreads();
  if (tid < HD) {
    const int h = tid;
    float e[MAXE];
    float m = -1e30f;
#pragma unroll
    for (int j = 0; j < MAXE; j++) {
      if (j < k) {
        float v = se[j][h] + edv[h];
        v = v >= 0.f ? v : 0.2f * v;   // leaky_relu 0.2
        e[j] = v;
        m = fmaxf(m, v);
      }
    }
    float denom = 0.f;
#pragma unroll
    for (int j = 0; j < MAXE; j++) {
      if (j < k) { e[j] = expf(e[j] - m); denom += e[j]; }
    }
    float inv = 1.f / fmaxf(denom, 1e-16f);
#pragma unroll
    for (int j = 0; j < MAXE; j++) {
      if (j < k) al[j][h] = e[j] * inv;
    }
  }
  __syncthreads();
  const float4* Hb = (const float4*)(H + (size_t)b * NN * FDIM);
  const int h = tid >> 5;
  float4 acc = ((const float4*)b1)[tid];
  for (int j = 0; j < k; j++) {
    float a = al[j][h];
    float4 v = Hb[(size_t)ss[j] * (FDIM / 4) + tid];
    acc.x += a * v.x; acc.y += a * v.y; acc.z += a * v.z; acc.w += a * v.w;
  }
  acc.x = acc.x > 0.f ? acc.x : expm1f(acc.x);
  acc.y = acc.y > 0.f ? acc.y : expm1f(acc.y);
  acc.z = acc.z > 0.f ? acc.z : expm1f(acc.z);
  acc.w = acc.w > 0.f ? acc.w : expm1f(acc.w);
  us4 hv, lv;
  hv.x = f2bf(acc.x); lv.x = f2bf(acc.x - bf2f(hv.x));
  hv.y = f2bf(acc.y); lv.y = f2bf(acc.y - bf2f(hv.y));
  hv.z = f2bf(acc.z); lv.z = f2bf(acc.z - bf2f(hv.z));
  hv.w = f2bf(acc.w); lv.w = f2bf(acc.w - bf2f(hv.w));
  *(us4*)&Zh[(size_t)bid * FDIM + (tid << 2)] = hv;
  *(us4*)&Zl[(size_t)bid * FDIM + (tid << 2)] = lv;
}

// ---------------------------------------------------------------------------
// K6: attn2 softmax+aggregate — block per (graph,node); thread = channel
// ---------------------------------------------------------------------------
__global__ void __launch_bounds__(256) attn2_agg(
    const float* __restrict__ H2, const int* __restrict__ srcs_g,
    const int* __restrict__ cnt_g, const float* __restrict__ es2p,
    const float* __restrict__ ed2p, const float* __restrict__ b2,
    float* __restrict__ Z2) {
  const int bid = blockIdx.x;
  const int b = bid / NN;
  const int tid = threadIdx.x;
  __shared__ int ss[MAXE];
  __shared__ float se[MAXE];
  __shared__ float al[MAXE];
  const int k = cnt_g[bid];
  if (tid < MAXE) ss[tid] = srcs_g[(size_t)bid * MAXE + tid];
  __syncthreads();
  if (tid < MAXE) {
    size_t base = ((size_t)b * NN + ss[tid]) * 4;
    se[tid] = es2p[base] + es2p[base + 1] + es2p[base + 2] + es2p[base + 3];
  }
  __syncthreads();
  if (tid == 0) {
    size_t base = (size_t)bid * 4;
    float ed = ed2p[base] + ed2p[base + 1] + ed2p[base + 2] + ed2p[base + 3];
    float e[MAXE];
    float m = -1e30f;
#pragma unroll
    for (int j = 0; j < MAXE; j++) {
      if (j < k) {
        float v = se[j] + ed;
        v = v >= 0.f ? v : 0.2f * v;
        e[j] = v;
        m = fmaxf(m, v);
      }
    }
    float denom = 0.f;
#pragma unroll
    for (int j = 0; j < MAXE; j++) {
      if (j < k) { e[j] = expf(e[j] - m); denom += e[j]; }
    }
    float inv = 1.f / fmaxf(denom, 1e-16f);
#pragma unroll
    for (int j = 0; j < MAXE; j++) {
      if (j < k) al[j] = e[j] * inv;
    }
  }
  __syncthreads();
  const float* Hb = H2 + (size_t)b * NN * ODIM;
  float acc = b2[tid];
  for (int j = 0; j < k; j++)
    acc += al[j] * Hb[(size_t)ss[j] * ODIM + tid];
  acc = acc > 0.f ? acc : expm1f(acc);
  Z2[(size_t)bid * ODIM + tid] = acc;
}

// ---------------------------------------------------------------------------
// K7: classifier with fused mean pool
// ---------------------------------------------------------------------------
__global__ void __launch_bounds__(256) classifier_kernel(
    const float* __restrict__ Z2, const float* __restrict__ Wc1,
    const float* __restrict__ bc1, const float* __restrict__ Wc2,
    const float* __restrict__ bc2, float* __restrict__ out) {
  const int b = blockIdx.x, tid = threadIdx.x;
  __shared__ float p[ODIM];
  __shared__ float t[ODIM];
  float s = 0.f;
  for (int i = 0; i < NN; i++)
    s += Z2[((size_t)b * NN + i) * ODIM + tid];
  p[tid] = s * (1.f / 49.f);
  __syncthreads();
  float a = bc1[tid];
  for (int c = 0; c < ODIM; c++) a += p[c] * Wc1[(size_t)c * ODIM + tid];
  t[tid] = a > 0.f ? a : 0.f;
  __syncthreads();
  if (tid < NC) {
    float o = bc2[tid];
    for (int j = 0; j < ODIM; j++) o += t[j] * Wc2[(size_t)j * NC + tid];
    out[(size_t)b * NC + tid] = o;
  }
}

// ---------------------------------------------------------------------------
extern "C" void kernel_launch(void* const* d_in, const int* in_sizes, int n_in,
                              void* d_out, int out_size, void* d_ws, size_t ws_size,
                              hipStream_t stream) {
  const float* feat   = (const float*)d_in[0];
  const float* W1     = (const float*)d_in[1];
  const float* a_src1 = (const float*)d_in[2];
  const float* a_dst1 = (const float*)d_in[3];
  const float* b1     = (const float*)d_in[4];
  const float* W2     = (const float*)d_in[5];
  const float* a_src2 = (const float*)d_in[6];
  const float* a_dst2 = (const float*)d_in[7];
  const float* b2     = (const float*)d_in[8];
  const float* Wc1    = (const float*)d_in[9];
  const float* bc1    = (const float*)d_in[10];
  const float* Wc2    = (const float*)d_in[11];
  const float* bc2    = (const float*)d_in[12];

  const int B = in_sizes[0] / (FDIM * NN);   // 256
  const int M = B * NN;                       // 12544

  const size_t xE = (size_t)M * FDIM;
  float* X  = (float*)d_ws;                   // fp32 X; later H2 (M*ODIM)
  float* H1 = X + xE;                         // fp32 H1; later Z2 (M*ODIM)
  unsigned short* Xh = (unsigned short*)(H1 + xE);  // later Z1h
  unsigned short* Xl = Xh + xE;                     // later Z1l
  unsigned short* W1hT = Xl + xE;
  unsigned short* W1lT = W1hT + (size_t)FDIM * FDIM;
  unsigned short* W2hT = W1lT + (size_t)FDIM * FDIM;
  unsigned short* W2lT = W2hT + (size_t)ODIM * FDIM;
  int*   srcs_g = (int*)(W2lT + (size_t)ODIM * FDIM);
  int*   cnt_g  = srcs_g + (size_t)M * MAXE;
  float* es1p   = (float*)(cnt_g + M);            // [M][16]
  float* ed1p   = es1p + (size_t)M * 16;
  float* es2p   = ed1p + (size_t)M * 16;          // [M][4]
  float* ed2p   = es2p + (size_t)M * 4;
  // aliases (producer strictly after last reader of the original)
  float* H2  = X;      // X dead after knn_gemm1
  float* Z2  = H1;     // H1 dead after attn1_agg
  unsigned short* Z1h = Xh;  // Xh/Xl dead after gemm1
  unsigned short* Z1l = Xl;

  const int NWG1 = (M / 128) * (FDIM / 128);   // 784
  const int NWG2 = (M / 128) * (ODIM / 128);   // 196

  // 1: relu+transpose (X + bf16 split) + both weight transposes
  pre_kernel<<<4416, 256, 0, stream>>>(feat, X, Xh, Xl, W1, W1hT, W1lT,
                                       W2, W2hT, W2lT);
  // 2: knn (blocks 0..255, overlapped) + gemm1 H1 = X@W1 (+es1/ed1)
  knn_gemm1_kernel<<<B + NWG1, 256, 0, stream>>>(
      X, srcs_g, cnt_g, B,
      Xh, Xl, W1hT, W1lT, H1, M, FDIM, FDIM, NWG1,
      a_src1, a_dst1, es1p, ed1p);
  // 3: layer-1 softmax+aggregate -> Z1 bf16 hi/lo
  attn1_agg<<<M, 256, 0, stream>>>(H1, srcs_g, cnt_g, es1p, ed1p, b1, Z1h, Z1l);
  // 4: H2 = Z1 @ W2 (+es2/ed2 partials)  (into X buffer)
  gemm_kernel<<<NWG2, 256, 0, stream>>>(
      Z1h, Z1l, W2hT, W2lT, H2, M, ODIM, FDIM, a_src2, a_dst2, es2p, ed2p);
  // 5: layer-2 softmax+aggregate -> Z2 (into H1 buffer)
  attn2_agg<<<M, 256, 0, stream>>>(H2, srcs_g, cnt_g, es2p, ed2p, b2, Z2);
  // 6: mean pool + MLP classifier
  classifier_kernel<<<B, 256, 0, stream>>>(Z2, Wc1, bc1, Wc2, bc2, (float*)d_out);
}

// Round 18
// 310.469 us; speedup vs baseline: 1.2866x; 1.2866x over previous
//
#include <hip/hip_runtime.h>

#define GDIM 7
#define NN 49            // nodes per graph
#define FDIM 1024
#define HD 8
#define CD 128
#define ODIM 256
#define NC 14
#define MAXE 12          // max incoming edges: 8 spatial + 3 knn + self
#define KR 28            // knn rows per block (x2 row split)

typedef __attribute__((ext_vector_type(4))) float f32x4;
typedef __attribute__((ext_vector_type(8))) short s16x8;

struct us4 { unsigned short x, y, z, w; };

__device__ __forceinline__ unsigned short f2bf(float x) {
  unsigned u = __float_as_uint(x);
  return (unsigned short)((u + 0x7fffu + ((u >> 16) & 1u)) >> 16);  // RNE
}
__device__ __forceinline__ float bf2f(unsigned short h) {
  return __uint_as_float((unsigned)h << 16);
}

#define GLOAD_LDS16(g, l)                                          \
  __builtin_amdgcn_global_load_lds(                                \
      (const __attribute__((address_space(1))) void*)(g),          \
      (__attribute__((address_space(3))) void*)(l), 16, 0, 0)

// ---------------------------------------------------------------------------
// K1: pre-pass — relu+transpose (blocks 0..4095: fp32 X + bf16 hi/lo split),
//     wconvT W1 (4096..4351), wconvT W2 (4352..4415). r15-verified.
// ---------------------------------------------------------------------------
__device__ void relu_body(char* smem, int blk, const float* __restrict__ F,
                          float* __restrict__ X,
                          unsigned short* __restrict__ Xh,
                          unsigned short* __restrict__ Xl) {
  float* lds = (float*)smem;           // 64*49 floats
  const int b  = blk >> 4;
  const int f0 = (blk & 15) << 6;
  const int tid = threadIdx.x;
  const float* src = F + (size_t)b * FDIM * NN + (size_t)f0 * NN;
  for (int idx = tid; idx < 64 * NN; idx += 256) lds[idx] = src[idx];
  __syncthreads();
  for (int pass = 0; pass < 13; pass++) {
    int n = pass * 4 + (tid >> 6);
    int fi = tid & 63;
    if (n < NN) {
      float v = lds[fi * NN + n];
      v = v > 0.f ? v : 0.f;
      size_t o = ((size_t)b * NN + n) * FDIM + f0 + fi;
      X[o] = v;
      unsigned short h = f2bf(v);
      Xh[o] = h;
      Xl[o] = f2bf(v - bf2f(h));
    }
  }
}

__device__ void wconvT_body(const float* __restrict__ W, int K, int N,
                            unsigned short* __restrict__ WhT,
                            unsigned short* __restrict__ WlT, int blk,
                            float* t /* [64*65] */) {
  const int nbx = N >> 6;
  const int bx = blk % nbx, by = blk / nbx;
  const int r0 = by << 6, c0 = bx << 6;
  const int tid = threadIdx.x;
#pragma unroll
  for (int i = 0; i < 16; i++) {
    int r = i * 4 + (tid >> 6), c = tid & 63;
    t[r * 65 + c] = W[(size_t)(r0 + r) * N + c0 + c];
  }
  __syncthreads();
#pragma unroll
  for (int i = 0; i < 16; i++) {
    int n = i * 4 + (tid >> 6);
    int k = tid & 63;
    float x = t[k * 65 + n];
    unsigned short h = f2bf(x);
    size_t o = (size_t)(c0 + n) * K + r0 + k;
    WhT[o] = h;
    WlT[o] = f2bf(x - bf2f(h));
  }
}

__global__ void __launch_bounds__(256) pre_kernel(
    const float* __restrict__ F, float* __restrict__ X,
    unsigned short* __restrict__ Xh, unsigned short* __restrict__ Xl,
    const float* __restrict__ W1, unsigned short* __restrict__ W1hT,
    unsigned short* __restrict__ W1lT, const float* __restrict__ W2,
    unsigned short* __restrict__ W2hT, unsigned short* __restrict__ W2lT) {
  __shared__ __align__(16) char smem[16640];   // max(12544, 64*65*4)
  if (blockIdx.x < 4096) {
    relu_body(smem, blockIdx.x, F, X, Xh, Xl);
  } else if (blockIdx.x < 4352) {
    wconvT_body(W1, FDIM, FDIM, W1hT, W1lT, blockIdx.x - 4096, (float*)smem);
  } else {
    wconvT_body(W2, FDIM, ODIM, W2hT, W2lT, blockIdx.x - 4352, (float*)smem);
  }
}

// ---------------------------------------------------------------------------
// K2: kNN row-split x2 — grid B*2; block (b,p) computes Gram rows
//     [p*28, p*28+28) x 49, self-norms for all rows (register-accumulated),
//     then top-3 + edge-list emit for its own rows. 2 blocks/CU -> 2
//     waves/SIMD (2x latency hiding vs r15's monolithic 1/CU).
//     Register-tiled inner loop: thread = 2x4 stride-14 tile (r6-verified).
// ---------------------------------------------------------------------------
__global__ void __launch_bounds__(256) knn_kernel(
    const float* __restrict__ X, int* __restrict__ srcs_g,
    int* __restrict__ cnt_g) {
  const int gid = blockIdx.x;
  const int b = gid >> 1, p = gid & 1;
  const int tid = threadIdx.x;
  __shared__ float xs[56][68];
  __shared__ float gram[KR][57];
  __shared__ float sq[NN];
  const float* Xb = X + (size_t)b * NN * FDIM;

  const int tr = tid / 14, tc = tid % 14;   // active: tid < 196
  const int r0 = p * KR;
  float acc[2][4];
#pragma unroll
  for (int i = 0; i < 2; i++)
#pragma unroll
    for (int j = 0; j < 4; j++) acc[i][j] = 0.f;
  float sqacc = 0.f;

  for (int c0 = 0; c0 < FDIM; c0 += 64) {
    __syncthreads();
    for (int idx = tid; idx < NN * 16; idx += 256) {
      int n = idx >> 4, q = idx & 15;
      *(float4*)&xs[n][q << 2] =
          *(const float4*)&Xb[(size_t)n * FDIM + c0 + (q << 2)];
    }
    __syncthreads();
    if (tid < 196) {
#pragma unroll
      for (int k4 = 0; k4 < 64; k4 += 4) {
        float4 a[2], bb[4];
#pragma unroll
        for (int i = 0; i < 2; i++) a[i]  = *(const float4*)&xs[r0 + tr + 14 * i][k4];
#pragma unroll
        for (int j = 0; j < 4; j++) bb[j] = *(const float4*)&xs[tc + 14 * j][k4];
#pragma unroll
        for (int i = 0; i < 2; i++)
#pragma unroll
          for (int j = 0; j < 4; j++)
            acc[i][j] += a[i].x * bb[j].x + a[i].y * bb[j].y +
                         a[i].z * bb[j].z + a[i].w * bb[j].w;
      }
    }
    if (tid < NN) {
      const float* r = &xs[tid][0];
      float s = 0.f;
#pragma unroll 8
      for (int j = 0; j < 64; j++) s += r[j] * r[j];
      sqacc += s;
    }
  }
  if (tid < 196) {
#pragma unroll
    for (int i = 0; i < 2; i++)
#pragma unroll
      for (int j = 0; j < 4; j++) gram[tr + 14 * i][tc + 14 * j] = acc[i][j];
  }
  if (tid < NN) sq[tid] = sqacc;
  __syncthreads();
  if (tid < KR) {
    const int n = r0 + tid;
    if (n < NN) {
      const float sqn = sq[n];
      float d0 = 1e30f, d1 = 1e30f, d2 = 1e30f;
      int i0 = 0, i1 = 0, i2 = 0;
      for (int m = 0; m < NN; m++) {
        if (m == n) continue;
        float d = sqn + sq[m] - 2.f * gram[tid][m];
        if (d < d0)      { d2=d1; i2=i1; d1=d0; i1=i0; d0=d; i0=m; }
        else if (d < d1) { d2=d1; i2=i1; d1=d;  i1=m; }
        else if (d < d2) { d2=d;  i2=m; }
      }
      int srcs[MAXE];
      int r = n / GDIM, c = n % GDIM, k = 0;
      for (int dr = -1; dr <= 1; dr++)
        for (int dc = -1; dc <= 1; dc++) {
          if (dr == 0 && dc == 0) continue;
          int rr = r + dr, cc = c + dc;
          if (rr >= 0 && rr < GDIM && cc >= 0 && cc < GDIM)
            srcs[k++] = rr * GDIM + cc;
        }
      srcs[k++] = i0; srcs[k++] = i1; srcs[k++] = i2;
      srcs[k++] = n;   // self loop
      cnt_g[(size_t)b * NN + n] = k;
      for (int j = 0; j < MAXE; j++)
        srcs_g[((size_t)b * NN + n) * MAXE + j] = srcs[j < k ? j : 0];
    }
  }
}

// ---------------------------------------------------------------------------
// K3/K5: bf16x3-split MFMA GEMM, 128x128 tile, BK=64, XCD swizzle, XOR chunk
//   swizzle (r9: conflicts=0, VGPR 104). Epilogue emits es/ed partials.
// ---------------------------------------------------------------------------
__global__ void __launch_bounds__(256) gemm_bf16x3(
    const unsigned short* __restrict__ A_h, const unsigned short* __restrict__ A_l,
    const unsigned short* __restrict__ BT_h, const unsigned short* __restrict__ BT_l,
    float* __restrict__ C, int M, int N, int K,
    const float* __restrict__ av, const float* __restrict__ dv,
    float* __restrict__ esp, float* __restrict__ edp) {
  __shared__ unsigned short sAh[128][64], sAl[128][64];
  __shared__ unsigned short sBh[128][64], sBl[128][64];
  const int tid = threadIdx.x;
  const int w = tid >> 6, lane = tid & 63;
  const int nbx = N >> 7;
  const int nwg = gridDim.x;
  const int q = nwg >> 3, r = nwg & 7;
  const int xcd = blockIdx.x & 7, loc = blockIdx.x >> 3;
  const int wg = (xcd < r) ? (xcd * (q + 1) + loc)
                           : (r * (q + 1) + (xcd - r) * q + loc);
  const int bx = wg % nbx, by = wg / nbx;
  const int row0 = by << 7, col0 = bx << 7;
  const int wr = (w >> 1) << 6, wc = (w & 1) << 6;
  const int sgr = lane >> 3;
  const int schunk = lane & 7;
  const int fr = lane & 15;
  const int fq = lane >> 4;

  f32x4 acc[4][4];
#pragma unroll
  for (int m = 0; m < 4; m++)
#pragma unroll
    for (int n = 0; n < 4; n++) acc[m][n] = (f32x4){0.f, 0.f, 0.f, 0.f};

  for (int k0 = 0; k0 < K; k0 += 64) {
    __syncthreads();
#pragma unroll
    for (int i = 0; i < 4; i++) {
      const int rbase = (w << 5) + (i << 3);
      const int gr = rbase + sgr;
      const int sc = schunk ^ (gr & 7);
      const size_t ga = (size_t)(row0 + gr) * K + k0 + (sc << 3);
      GLOAD_LDS16(A_h + ga, &sAh[rbase][0]);
      GLOAD_LDS16(A_l + ga, &sAl[rbase][0]);
      const size_t gb = (size_t)(col0 + gr) * K + k0 + (sc << 3);
      GLOAD_LDS16(BT_h + gb, &sBh[rbase][0]);
      GLOAD_LDS16(BT_l + gb, &sBl[rbase][0]);
    }
    __syncthreads();
#pragma unroll
    for (int ks = 0; ks < 2; ks++) {
      const int cb = (ks << 2) + fq;
      s16x8 ah[4], al[4], bh[4], bl[4];
#pragma unroll
      for (int m = 0; m < 4; m++) {
        const int ra = wr + (m << 4) + fr;
        const int ca = (cb ^ (ra & 7)) << 3;
        ah[m] = *(const s16x8*)&sAh[ra][ca];
        al[m] = *(const s16x8*)&sAl[ra][ca];
        const int rb = wc + (m << 4) + fr;
        const int cbn = (cb ^ (rb & 7)) << 3;
        bh[m] = *(const s16x8*)&sBh[rb][cbn];
        bl[m] = *(const s16x8*)&sBl[rb][cbn];
      }
#pragma unroll
      for (int m = 0; m < 4; m++)
#pragma unroll
        for (int n = 0; n < 4; n++) {
          acc[m][n] = __builtin_amdgcn_mfma_f32_16x16x32_bf16(ah[m], bh[n], acc[m][n], 0, 0, 0);
          acc[m][n] = __builtin_amdgcn_mfma_f32_16x16x32_bf16(ah[m], bl[n], acc[m][n], 0, 0, 0);
          acc[m][n] = __builtin_amdgcn_mfma_f32_16x16x32_bf16(al[m], bh[n], acc[m][n], 0, 0, 0);
        }
    }
  }
  const int crow = fq << 2, ccol = fr;
#pragma unroll
  for (int m = 0; m < 4; m++)
#pragma unroll
    for (int n = 0; n < 4; n++)
#pragma unroll
      for (int v = 0; v < 4; v++)
        C[(size_t)(row0 + wr + (m << 4) + crow + v) * N + col0 + wc + (n << 4) + ccol] =
            acc[m][n][v];

  // fused es/ed partial dots (owner-computes, no atomics)
  const int pstride = N >> 6;
  const int part = (col0 + wc) >> 6;
  float asv[4], adv[4];
#pragma unroll
  for (int n = 0; n < 4; n++) {
    int cidx = col0 + wc + (n << 4) + fr;
    asv[n] = av[cidx];
    adv[n] = dv[cidx];
  }
#pragma unroll
  for (int m = 0; m < 4; m++)
#pragma unroll
    for (int v = 0; v < 4; v++) {
      float s = acc[m][0][v] * asv[0] + acc[m][1][v] * asv[1] +
                acc[m][2][v] * asv[2] + acc[m][3][v] * asv[3];
      float d = acc[m][0][v] * adv[0] + acc[m][1][v] * adv[1] +
                acc[m][2][v] * adv[2] + acc[m][3][v] * adv[3];
      s += __shfl_xor(s, 1); s += __shfl_xor(s, 2);
      s += __shfl_xor(s, 4); s += __shfl_xor(s, 8);
      d += __shfl_xor(d, 1); d += __shfl_xor(d, 2);
      d += __shfl_xor(d, 4); d += __shfl_xor(d, 8);
      if (fr == 0) {
        int row = row0 + wr + (m << 4) + (fq << 2) + v;
        esp[(size_t)row * pstride + part] = s;
        edp[(size_t)row * pstride + part] = d;
      }
    }
}

// ---------------------------------------------------------------------------
// K4: attn1 softmax+aggregate — block per (graph,node); Z1 as bf16 hi/lo
// ---------------------------------------------------------------------------
__global__ void __launch_bounds__(256) attn1_agg(
    const float* __restrict__ H, const int* __restrict__ srcs_g,
    const int* __restrict__ cnt_g, const float* __restrict__ es1p,
    const float* __restrict__ ed1p, const float* __restrict__ b1,
    unsigned short* __restrict__ Zh, unsigned short* __restrict__ Zl) {
  const int bid = blockIdx.x;          // = b*NN + i
  const int b = bid / NN;
  const int tid = threadIdx.x;
  __shared__ int ss[MAXE];
  __shared__ float se[MAXE][HD];
  __shared__ float edv[HD];
  __shared__ float al[MAXE][HD];
  const int k = cnt_g[bid];
  if (tid < MAXE) ss[tid] = srcs_g[(size_t)bid * MAXE + tid];
  __syncthreads();
  if (tid < MAXE * HD) {
    int j = tid >> 3, h = tid & 7;
    size_t base = ((size_t)b * NN + ss[j]) * 16 + h * 2;
    se[j][h] = es1p[base] + es1p[base + 1];
  }
  if (tid >= 128 && tid < 128 + HD) {
    int h = tid - 128;
    size_t base = (size_t)bid * 16 + h * 2;
    edv[h] = ed1p[base] + ed1p[base + 1];
  }
  __syncthreads();
  if (tid < HD) {
    const int h = tid;
    float e[MAXE];
    float m = -1e30f;
#pragma unroll
    for (int j = 0; j < MAXE; j++) {
      if (j < k) {
        float v = se[j][h] + edv[h];
        v = v >= 0.f ? v : 0.2f * v;   // leaky_relu 0.2
        e[j] = v;
        m = fmaxf(m, v);
      }
    }
    float denom = 0.f;
#pragma unroll
    for (int j = 0; j < MAXE; j++) {
      if (j < k) { e[j] = expf(e[j] - m); denom += e[j]; }
    }
    float inv = 1.f / fmaxf(denom, 1e-16f);
#pragma unroll
    for (int j = 0; j < MAXE; j++) {
      if (j < k) al[j][h] = e[j] * inv;
    }
  }
  __syncthreads();
  const float4* Hb = (const float4*)(H + (size_t)b * NN * FDIM);
  const int h = tid >> 5;
  float4 acc = ((const float4*)b1)[tid];
  for (int j = 0; j < k; j++) {
    float a = al[j][h];
    float4 v = Hb[(size_t)ss[j] * (FDIM / 4) + tid];
    acc.x += a * v.x; acc.y += a * v.y; acc.z += a * v.z; acc.w += a * v.w;
  }
  acc.x = acc.x > 0.f ? acc.x : expm1f(acc.x);
  acc.y = acc.y > 0.f ? acc.y : expm1f(acc.y);
  acc.z = acc.z > 0.f ? acc.z : expm1f(acc.z);
  acc.w = acc.w > 0.f ? acc.w : expm1f(acc.w);
  us4 hv, lv;
  hv.x = f2bf(acc.x); lv.x = f2bf(acc.x - bf2f(hv.x));
  hv.y = f2bf(acc.y); lv.y = f2bf(acc.y - bf2f(hv.y));
  hv.z = f2bf(acc.z); lv.z = f2bf(acc.z - bf2f(hv.z));
  hv.w = f2bf(acc.w); lv.w = f2bf(acc.w - bf2f(hv.w));
  *(us4*)&Zh[(size_t)bid * FDIM + (tid << 2)] = hv;
  *(us4*)&Zl[(size_t)bid * FDIM + (tid << 2)] = lv;
}

// ---------------------------------------------------------------------------
// K6: attn2 softmax+aggregate — block per (graph,node); thread = channel
// ---------------------------------------------------------------------------
__global__ void __launch_bounds__(256) attn2_agg(
    const float* __restrict__ H2, const int* __restrict__ srcs_g,
    const int* __restrict__ cnt_g, const float* __restrict__ es2p,
    const float* __restrict__ ed2p, const float* __restrict__ b2,
    float* __restrict__ Z2) {
  const int bid = blockIdx.x;
  const int b = bid / NN;
  const int tid = threadIdx.x;
  __shared__ int ss[MAXE];
  __shared__ float se[MAXE];
  __shared__ float al[MAXE];
  const int k = cnt_g[bid];
  if (tid < MAXE) ss[tid] = srcs_g[(size_t)bid * MAXE + tid];
  __syncthreads();
  if (tid < MAXE) {
    size_t base = ((size_t)b * NN + ss[tid]) * 4;
    se[tid] = es2p[base] + es2p[base + 1] + es2p[base + 2] + es2p[base + 3];
  }
  __syncthreads();
  if (tid == 0) {
    size_t base = (size_t)bid * 4;
    float ed = ed2p[base] + ed2p[base + 1] + ed2p[base + 2] + ed2p[base + 3];
    float e[MAXE];
    float m = -1e30f;
#pragma unroll
    for (int j = 0; j < MAXE; j++) {
      if (j < k) {
        float v = se[j] + ed;
        v = v >= 0.f ? v : 0.2f * v;
        e[j] = v;
        m = fmaxf(m, v);
      }
    }
    float denom = 0.f;
#pragma unroll
    for (int j = 0; j < MAXE; j++) {
      if (j < k) { e[j] = expf(e[j] - m); denom += e[j]; }
    }
    float inv = 1.f / fmaxf(denom, 1e-16f);
#pragma unroll
    for (int j = 0; j < MAXE; j++) {
      if (j < k) al[j] = e[j] * inv;
    }
  }
  __syncthreads();
  const float* Hb = H2 + (size_t)b * NN * ODIM;
  float acc = b2[tid];
  for (int j = 0; j < k; j++)
    acc += al[j] * Hb[(size_t)ss[j] * ODIM + tid];
  acc = acc > 0.f ? acc : expm1f(acc);
  Z2[(size_t)bid * ODIM + tid] = acc;
}

// ---------------------------------------------------------------------------
// K7: classifier with fused mean pool
// ---------------------------------------------------------------------------
__global__ void __launch_bounds__(256) classifier_kernel(
    const float* __restrict__ Z2, const float* __restrict__ Wc1,
    const float* __restrict__ bc1, const float* __restrict__ Wc2,
    const float* __restrict__ bc2, float* __restrict__ out) {
  const int b = blockIdx.x, tid = threadIdx.x;
  __shared__ float p[ODIM];
  __shared__ float t[ODIM];
  float s = 0.f;
  for (int i = 0; i < NN; i++)
    s += Z2[((size_t)b * NN + i) * ODIM + tid];
  p[tid] = s * (1.f / 49.f);
  __syncthreads();
  float a = bc1[tid];
  for (int c = 0; c < ODIM; c++) a += p[c] * Wc1[(size_t)c * ODIM + tid];
  t[tid] = a > 0.f ? a : 0.f;
  __syncthreads();
  if (tid < NC) {
    float o = bc2[tid];
    for (int j = 0; j < ODIM; j++) o += t[j] * Wc2[(size_t)j * NC + tid];
    out[(size_t)b * NC + tid] = o;
  }
}

// ---------------------------------------------------------------------------
extern "C" void kernel_launch(void* const* d_in, const int* in_sizes, int n_in,
                              void* d_out, int out_size, void* d_ws, size_t ws_size,
                              hipStream_t stream) {
  const float* feat   = (const float*)d_in[0];
  const float* W1     = (const float*)d_in[1];
  const float* a_src1 = (const float*)d_in[2];
  const float* a_dst1 = (const float*)d_in[3];
  const float* b1     = (const float*)d_in[4];
  const float* W2     = (const float*)d_in[5];
  const float* a_src2 = (const float*)d_in[6];
  const float* a_dst2 = (const float*)d_in[7];
  const float* b2     = (const float*)d_in[8];
  const float* Wc1    = (const float*)d_in[9];
  const float* bc1    = (const float*)d_in[10];
  const float* Wc2    = (const float*)d_in[11];
  const float* bc2    = (const float*)d_in[12];

  const int B = in_sizes[0] / (FDIM * NN);   // 256
  const int M = B * NN;                       // 12544

  const size_t xE = (size_t)M * FDIM;
  float* X  = (float*)d_ws;                   // fp32 X; later H2 (M*ODIM)
  float* H1 = X + xE;                         // fp32 H1; later Z2 (M*ODIM)
  unsigned short* Xh = (unsigned short*)(H1 + xE);  // later Z1h
  unsigned short* Xl = Xh + xE;                     // later Z1l
  unsigned short* W1hT = Xl + xE;
  unsigned short* W1lT = W1hT + (size_t)FDIM * FDIM;
  unsigned short* W2hT = W1lT + (size_t)FDIM * FDIM;
  unsigned short* W2lT = W2hT + (size_t)ODIM * FDIM;
  int*   srcs_g = (int*)(W2lT + (size_t)ODIM * FDIM);
  int*   cnt_g  = srcs_g + (size_t)M * MAXE;
  float* es1p   = (float*)(cnt_g + M);            // [M][16]
  float* ed1p   = es1p + (size_t)M * 16;
  float* es2p   = ed1p + (size_t)M * 16;          // [M][4]
  float* ed2p   = es2p + (size_t)M * 4;
  // aliases (producer strictly after last reader of the original)
  float* H2  = X;      // X dead after knn_kernel
  float* Z2  = H1;     // H1 dead after attn1_agg
  unsigned short* Z1h = Xh;  // Xh/Xl dead after gemm1
  unsigned short* Z1l = Xl;

  const int NWG1 = (M / 128) * (FDIM / 128);   // 784
  const int NWG2 = (M / 128) * (ODIM / 128);   // 196

  // 1: relu+transpose (X + bf16 split) + both weight transposes
  pre_kernel<<<4416, 256, 0, stream>>>(feat, X, Xh, Xl, W1, W1hT, W1lT,
                                       W2, W2hT, W2lT);
  // 2: Gram row-split x2 + top-3 + edge lists
  knn_kernel<<<B * 2, 256, 0, stream>>>(X, srcs_g, cnt_g);
  // 3: H1 = X @ W1 (+es1/ed1 partials)
  gemm_bf16x3<<<NWG1, 256, 0, stream>>>(
      Xh, Xl, W1hT, W1lT, H1, M, FDIM, FDIM, a_src1, a_dst1, es1p, ed1p);
  // 4: layer-1 softmax+aggregate -> Z1 bf16 hi/lo
  attn1_agg<<<M, 256, 0, stream>>>(H1, srcs_g, cnt_g, es1p, ed1p, b1, Z1h, Z1l);
  // 5: H2 = Z1 @ W2 (+es2/ed2 partials)  (into X buffer)
  gemm_bf16x3<<<NWG2, 256, 0, stream>>>(
      Z1h, Z1l, W2hT, W2lT, H2, M, ODIM, FDIM, a_src2, a_dst2, es2p, ed2p);
  // 6: layer-2 softmax+aggregate -> Z2 (into H1 buffer)
  attn2_agg<<<M, 256, 0, stream>>>(H2, srcs_g, cnt_g, es2p, ed2p, b2, Z2);
  // 7: mean pool + MLP classifier
  classifier_kernel<<<B, 256, 0, stream>>>(Z2, Wc1, bc1, Wc2, bc2, (float*)d_out);
}